// Round 6
// baseline (660.757 us; speedup 1.0000x reference)
//
#include <hip/hip_runtime.h>
#include <stdint.h>

#define B_ 8
#define C_ 256
#define N_ 4096
#define M_ 4096
#define NT 128
#define MT 64
#define L2E 1.44269504f

typedef _Float16 f16x8 __attribute__((ext_vector_type(8)));
typedef _Float16 f16x4 __attribute__((ext_vector_type(4)));
typedef _Float16 f16x2 __attribute__((ext_vector_type(2)));
typedef float f32x16 __attribute__((ext_vector_type(16)));
typedef unsigned int u32x4 __attribute__((ext_vector_type(4)));

__device__ __forceinline__ void async16(const _Float16* g, _Float16* l) {
    __builtin_amdgcn_global_load_lds(
        (const __attribute__((address_space(1))) void*)g,
        (__attribute__((address_space(3))) void*)l, 16, 0, 0);
}

// permlane32_swap: a' = [a_lo, b_lo], b' = [a_hi, b_hi]
__device__ __forceinline__ void plswap(unsigned &a, unsigned &b) {
    auto r = __builtin_amdgcn_permlane32_swap(a, b, false, false);
    a = r[0];
    b = r[1];
}

// fused pre-pass: blocks [0,2048) transpose xs -> kt [B,M,C] fp16;
//                 blocks [2048,10240) convert ys -> vb [B,C,M] fp16
__global__ __launch_bounds__(256) void kPre(const float* __restrict__ xs,
                                            const float* __restrict__ ys,
                                            _Float16* __restrict__ kt,
                                            _Float16* __restrict__ vb) {
    int bx = blockIdx.x;
    int t = threadIdx.x;
    if (bx < 2048) {
        __shared__ float tile[64][65];
        int b = bx >> 8, rem = bx & 255;
        int c0 = (rem >> 6) * 64, m0 = (rem & 63) * 64;
        int cl = t >> 4, m4 = (t & 15) * 4;
#pragma unroll
        for (int i = 0; i < 4; i++) {
            int c = c0 + cl + i * 16;
            const float4 v = *(const float4*)(xs + ((size_t)(b * C_ + c) * M_) + m0 + m4);
            tile[m4 + 0][cl + i * 16] = v.x;
            tile[m4 + 1][cl + i * 16] = v.y;
            tile[m4 + 2][cl + i * 16] = v.z;
            tile[m4 + 3][cl + i * 16] = v.w;
        }
        __syncthreads();
        int ml = t >> 4, c4 = (t & 15) * 4;
#pragma unroll
        for (int i = 0; i < 4; i++) {
            int m = m0 + ml + i * 16;
            f16x4 o;
            o[0] = (_Float16)tile[ml + i * 16][c4 + 0];
            o[1] = (_Float16)tile[ml + i * 16][c4 + 1];
            o[2] = (_Float16)tile[ml + i * 16][c4 + 2];
            o[3] = (_Float16)tile[ml + i * 16][c4 + 3];
            *(f16x4*)(kt + ((size_t)(b * M_ + m) * C_) + c0 + c4) = o;
        }
    } else {
        size_t i = ((size_t)(bx - 2048) * 256 + t) * 4;
        float4 v = *(const float4*)(ys + i);
        f16x4 o;
        o[0] = (_Float16)v.x; o[1] = (_Float16)v.y;
        o[2] = (_Float16)v.z; o[3] = (_Float16)v.w;
        *(f16x4*)(vb + i) = o;
    }
}

// 32x32x16-MFMA flash attention, P never touches LDS.
// One 512-thread block per CU (grid 256). Wave w: n-strip ns=w&3 (32 n),
// c-half ch=w>>2 (128 c). Each wave computes the FULL 64-m S^T block for its
// n-strip (redundant across the ch pair -> softmax is 100% wave-local:
// per-lane running max/sum, ONE shfl_xor(32), no sAlpha/sFlag/sL/atomics).
// P is repacked in-register into PV B-fragments via permlane32_swap (lane
// pair l/l^32 holds complementary m-halves of the 32x32 C/D layout).
// V is read straight from L2 (vb[b] is XCD-resident). K staged via
// global_load_lds double-buffer; ONE barrier + one vmcnt(0) per iteration.
__global__ __launch_bounds__(512, 2) void kAttn(const float* __restrict__ h,
                                                const _Float16* __restrict__ kt,
                                                const _Float16* __restrict__ vb,
                                                float* __restrict__ out) {
    __shared__ _Float16 sK[2][MT * 256];   // 64 KB, 16B chunks XOR-swizzled by row&31

    const int t = threadIdx.x;
    const int w = t >> 6, lane = t & 63, hh = lane >> 5, l31 = lane & 31;
    const int b = blockIdx.x & 7;          // batch -> XCD (kt[b]+vb[b] L2-resident)
    const int n0 = (blockIdx.x >> 3) * NT;
    const int ns = w & 3, ch = w >> 2;

    const _Float16* srcKb = kt + (size_t)b * M_ * C_;
    const _Float16* srcVb = vb + (size_t)b * C_ * M_;

    // ---- issue K0 -> sK[0] (overlaps Q load below) ----
#pragma unroll
    for (int j = 0; j < 4; j++) {
        int row = w * 8 + j * 2 + hh;
        int logi = l31 ^ (row & 31);
        async16(srcKb + (size_t)row * C_ + logi * 8, &sK[0][(w * 8 + j * 2) * 256]);
    }

    // ---- Q fragments direct from global (coalesced across lanes; one-time) ----
    // B-frag of 32x32x16: col = l31 -> n = n0+ns*32+l31 ; k = ks*16 + hh*8 + i -> channel c
    f16x8 qf[16];
    {
        const float* hq = h + (size_t)b * C_ * N_ + n0 + ns * 32 + l31;
#pragma unroll
        for (int ks = 0; ks < 16; ks++) {
            f16x8 q;
#pragma unroll
            for (int i = 0; i < 8; i++)
                q[i] = (_Float16)hq[(size_t)(ks * 16 + hh * 8 + i) * N_];
            qf[ks] = q;
        }
    }

    f32x16 o[4];
#pragma unroll
    for (int cq = 0; cq < 4; cq++)
#pragma unroll
        for (int r = 0; r < 16; r++) o[cq][r] = 0.f;

    float mst = -3.0e38f, lp = 0.f;

    for (int it = 0; it < M_ / MT; it++) {
        const int cur = it & 1, nxt = cur ^ 1;
        const int m0i = it * MT;
        // single barrier: own K(it) staging drained per-wave, then all waves synced
        asm volatile("s_waitcnt vmcnt(0) lgkmcnt(0)" ::: "memory");
        __builtin_amdgcn_s_barrier();

        // ---- V(it) fragments, issued FIRST (oldest vmem -> PV waits vmcnt(4),
        //      K prefetch stays in flight through PV) ----
        // A-frag: row = l31 -> c = ch*128+cq*32+l31 ; k = ks*16 + hh*8 + i -> m
        f16x8 vf[4][4];
#pragma unroll
        for (int cq = 0; cq < 4; cq++)
#pragma unroll
            for (int ks = 0; ks < 4; ks++)
                vf[cq][ks] = *(const f16x8*)(srcVb + (size_t)(ch * 128 + cq * 32 + l31) * M_
                                             + m0i + ks * 16 + hh * 8);
        __builtin_amdgcn_sched_barrier(0);   // pin V-issue before K-issue

        // ---- K(it+1) prefetch ----
        if (it + 1 < M_ / MT) {
            const _Float16* srcK = srcKb + (size_t)(m0i + MT) * C_;
#pragma unroll
            for (int j = 0; j < 4; j++) {
                int row = w * 8 + j * 2 + hh;
                int logi = l31 ^ (row & 31);
                async16(srcK + (size_t)row * C_ + logi * 8, &sK[nxt][(w * 8 + j * 2) * 256]);
            }
        }

        // ---- S^T = K·Q^T for full 64 m x 32 n (2 quadrant accumulators) ----
        // C/D: col = l31 = n ; row(m) = mh*32 + (reg&3) + 8*(reg>>2) + 4*hh
        f32x16 sm[2];
#pragma unroll
        for (int mh = 0; mh < 2; mh++)
#pragma unroll
            for (int r = 0; r < 16; r++) sm[mh][r] = 0.f;
        __builtin_amdgcn_s_setprio(1);
#pragma unroll
        for (int ks = 0; ks < 16; ks++)
#pragma unroll
            for (int mh = 0; mh < 2; mh++) {
                f16x8 bk = *(const f16x8*)(&sK[cur][(mh * 32 + l31) * 256
                                                    + (((ks * 2 + hh) ^ l31) << 3)]);
                sm[mh] = __builtin_amdgcn_mfma_f32_32x32x16_f16(bk, qf[ks], sm[mh], 0, 0, 0);
            }
        __builtin_amdgcn_s_setprio(0);

        // ---- in-register online softmax (lane pair l/l^32 holds all 64 m) ----
        float tm[8];
#pragma unroll
        for (int j = 0; j < 8; j++)
            tm[j] = fmaxf(fmaxf(sm[0][j], sm[0][j + 8]), fmaxf(sm[1][j], sm[1][j + 8]));
#pragma unroll
        for (int j = 0; j < 4; j++) tm[j] = fmaxf(tm[j], tm[j + 4]);
        float rowmax = fmaxf(fmaxf(tm[0], tm[1]), fmaxf(tm[2], tm[3]));
        rowmax = fmaxf(rowmax, __shfl_xor(rowmax, 32, 64));
        float al = 1.0f;
        if (rowmax > mst) { al = exp2f((mst - rowmax) * L2E); mst = rowmax; }
        const float mb = mst * L2E;
#pragma unroll
        for (int mh = 0; mh < 2; mh++)
#pragma unroll
            for (int r = 0; r < 16; r++)
                sm[mh][r] = exp2f(sm[mh][r] * L2E - mb);
        float tp[8];
#pragma unroll
        for (int j = 0; j < 8; j++)
            tp[j] = (sm[0][j] + sm[0][j + 8]) + (sm[1][j] + sm[1][j + 8]);
#pragma unroll
        for (int j = 0; j < 4; j++) tp[j] += tp[j + 4];
        float ps = (tp[0] + tp[1]) + (tp[2] + tp[3]);
        ps += __shfl_xor(ps, 32, 64);
        lp = lp * al + ps;

        if (al != 1.0f) {
#pragma unroll
            for (int cq = 0; cq < 4; cq++)
#pragma unroll
                for (int r = 0; r < 16; r++) o[cq][r] *= al;
        }

        // ---- pack P -> PV B-frags in registers (no LDS) ----
        // pk[j] = f16 pair of m {base+2j*? } per derivation: pk[0..7] cover the
        // quadrant's m in C/D reg order; swap(pk[j], pk[j+2]) completes the
        // cross-half (l <-> l^32) redistribution for B-frag k-order.
        f16x8 pfr[4];
#pragma unroll
        for (int mh = 0; mh < 2; mh++) {
            unsigned pk[8];
#pragma unroll
            for (int j = 0; j < 8; j++) {
                f16x2 pr;
                pr[0] = (_Float16)sm[mh][2 * j];
                pr[1] = (_Float16)sm[mh][2 * j + 1];
                pk[j] = __builtin_bit_cast(unsigned, pr);
            }
            plswap(pk[0], pk[2]);
            plswap(pk[1], pk[3]);
            plswap(pk[4], pk[6]);
            plswap(pk[5], pk[7]);
            u32x4 t0, t1;
            t0[0] = pk[0]; t0[1] = pk[1]; t0[2] = pk[2]; t0[3] = pk[3];
            t1[0] = pk[4]; t1[1] = pk[5]; t1[2] = pk[6]; t1[3] = pk[7];
            pfr[2 * mh]     = __builtin_bit_cast(f16x8, t0);
            pfr[2 * mh + 1] = __builtin_bit_cast(f16x8, t1);
        }

        // ---- O += V·P^T (pure register MFMA; LDS idle) ----
        __builtin_amdgcn_s_setprio(1);
#pragma unroll
        for (int ks = 0; ks < 4; ks++)
#pragma unroll
            for (int cq = 0; cq < 4; cq++)
                o[cq] = __builtin_amdgcn_mfma_f32_32x32x16_f16(vf[cq][ks], pfr[ks], o[cq], 0, 0, 0);
        __builtin_amdgcn_s_setprio(0);
    }

    // ---- epilogue: fully lane-local normalize + store ----
    const float linv = 1.0f / lp;
#pragma unroll
    for (int cq = 0; cq < 4; cq++)
#pragma unroll
        for (int r = 0; r < 16; r++) {
            int c = ch * 128 + cq * 32 + (r & 3) + 8 * (r >> 2) + 4 * hh;
            out[((size_t)(b * C_ + c)) * N_ + n0 + ns * 32 + l31] = o[cq][r] * linv;
        }
}

extern "C" void kernel_launch(void* const* d_in, const int* in_sizes, int n_in,
                              void* d_out, int out_size, void* d_ws, size_t ws_size,
                              hipStream_t stream) {
    const float* h  = (const float*)d_in[0];
    const float* xs = (const float*)d_in[1];
    const float* ys = (const float*)d_in[2];
    float* out = (float*)d_out;

    _Float16* kt  = (_Float16*)d_ws;                    // [B,M,C] fp16: 16 MB
    _Float16* vbb = kt + (size_t)B_ * M_ * C_;          // [B,C,M] fp16: 16 MB

    kPre<<<dim3(2048 + 8192), 256, 0, stream>>>(xs, ys, kt, vbb);
    kAttn<<<dim3(B_ * (N_ / NT)), 512, 0, stream>>>(h, kt, vbb, out);
}

// Round 7
// 411.466 us; speedup vs baseline: 1.6059x; 1.6059x over previous
//
#include <hip/hip_runtime.h>
#include <stdint.h>

#define B_ 8
#define C_ 256
#define N_ 4096
#define M_ 4096
#define NT 128
#define MT 64
#define L2E 1.44269504f

typedef _Float16 f16x8 __attribute__((ext_vector_type(8)));
typedef _Float16 f16x4 __attribute__((ext_vector_type(4)));
typedef _Float16 f16x2 __attribute__((ext_vector_type(2)));
typedef float f32x16 __attribute__((ext_vector_type(16)));
typedef unsigned int u32x4 __attribute__((ext_vector_type(4)));

__device__ __forceinline__ void async16(const _Float16* g, _Float16* l) {
    __builtin_amdgcn_global_load_lds(
        (const __attribute__((address_space(1))) void*)g,
        (__attribute__((address_space(3))) void*)l, 16, 0, 0);
}

// permlane32_swap: a' = [a_lo, b_lo], b' = [a_hi, b_hi]
__device__ __forceinline__ void plswap(unsigned &a, unsigned &b) {
    auto r = __builtin_amdgcn_permlane32_swap(a, b, false, false);
    a = r[0];
    b = r[1];
}

// fused pre-pass: blocks [0,2048) transpose xs -> kt [B,M,C] fp16;
//                 blocks [2048,10240) convert ys -> vb [B,C,M] fp16
__global__ __launch_bounds__(256) void kPre(const float* __restrict__ xs,
                                            const float* __restrict__ ys,
                                            _Float16* __restrict__ kt,
                                            _Float16* __restrict__ vb) {
    int bx = blockIdx.x;
    int t = threadIdx.x;
    if (bx < 2048) {
        __shared__ float tile[64][65];
        int b = bx >> 8, rem = bx & 255;
        int c0 = (rem >> 6) * 64, m0 = (rem & 63) * 64;
        int cl = t >> 4, m4 = (t & 15) * 4;
#pragma unroll
        for (int i = 0; i < 4; i++) {
            int c = c0 + cl + i * 16;
            const float4 v = *(const float4*)(xs + ((size_t)(b * C_ + c) * M_) + m0 + m4);
            tile[m4 + 0][cl + i * 16] = v.x;
            tile[m4 + 1][cl + i * 16] = v.y;
            tile[m4 + 2][cl + i * 16] = v.z;
            tile[m4 + 3][cl + i * 16] = v.w;
        }
        __syncthreads();
        int ml = t >> 4, c4 = (t & 15) * 4;
#pragma unroll
        for (int i = 0; i < 4; i++) {
            int m = m0 + ml + i * 16;
            f16x4 o;
            o[0] = (_Float16)tile[ml + i * 16][c4 + 0];
            o[1] = (_Float16)tile[ml + i * 16][c4 + 1];
            o[2] = (_Float16)tile[ml + i * 16][c4 + 2];
            o[3] = (_Float16)tile[ml + i * 16][c4 + 3];
            *(f16x4*)(kt + ((size_t)(b * M_ + m) * C_) + c0 + c4) = o;
        }
    } else {
        size_t i = ((size_t)(bx - 2048) * 256 + t) * 4;
        float4 v = *(const float4*)(ys + i);
        f16x4 o;
        o[0] = (_Float16)v.x; o[1] = (_Float16)v.y;
        o[2] = (_Float16)v.z; o[3] = (_Float16)v.w;
        *(f16x4*)(vb + i) = o;
    }
}

// 32x32x16-MFMA flash attention, P never touches LDS. Spill-free edition:
// __launch_bounds__(512,1): HIP arg2 = min BLOCKS/CU (CUDA semantics, verified
// R5/R6: (512,4)->cap64, (512,2)->cap128). (512,1) -> VGPR cap 256.
// Peak live regs ~210: qf 64 + o 64 + (sm 32 | pfr 16) + V half 32 + temps.
// V is loaded in two named halves (static indexing only, rule #20):
//   vA (cq 0,1) issued right after barrier -> latency hidden under QK^T;
//   vB (cq 2,3) issued after P-pack       -> latency hidden under PV first half.
// Wave w: n-strip ns=w&3 (32 n), c-half ch=w>>2 (128 c). Each wave computes the
// full 64-m S^T block for its n-strip (redundant across ch pair -> softmax is
// 100% wave-local: ONE shfl_xor(32), no LDS P, no flags/atomics).
// K staged via global_load_lds dbuf; ONE barrier + one vmcnt(0) per iteration.
__global__ __launch_bounds__(512, 1) void kAttn(const float* __restrict__ h,
                                                const _Float16* __restrict__ kt,
                                                const _Float16* __restrict__ vb,
                                                float* __restrict__ out) {
    __shared__ _Float16 sK[2][MT * 256];   // 64 KB, 16B chunks XOR-swizzled by row&31

    const int t = threadIdx.x;
    const int w = t >> 6, lane = t & 63, hh = lane >> 5, l31 = lane & 31;
    const int b = blockIdx.x & 7;          // batch -> XCD (kt[b]+vb[b] L2-resident)
    const int n0 = (blockIdx.x >> 3) * NT;
    const int ns = w & 3, ch = w >> 2;

    const _Float16* srcKb = kt + (size_t)b * M_ * C_;
    const _Float16* srcVb = vb + (size_t)b * C_ * M_;

    // ---- issue K0 -> sK[0] (overlaps Q load below) ----
#pragma unroll
    for (int j = 0; j < 4; j++) {
        int row = w * 8 + j * 2 + hh;
        int logi = l31 ^ (row & 31);
        async16(srcKb + (size_t)row * C_ + logi * 8, &sK[0][(w * 8 + j * 2) * 256]);
    }

    // ---- Q fragments direct from global (coalesced across lanes; one-time) ----
    // B-frag of 32x32x16: col = l31 -> n = n0+ns*32+l31 ; k = ks*16 + hh*8 + i -> channel c
    f16x8 qf[16];
    {
        const float* hq = h + (size_t)b * C_ * N_ + n0 + ns * 32 + l31;
#pragma unroll
        for (int ks = 0; ks < 16; ks++) {
            f16x8 q;
#pragma unroll
            for (int i = 0; i < 8; i++)
                q[i] = (_Float16)hq[(size_t)(ks * 16 + hh * 8 + i) * N_];
            qf[ks] = q;
        }
    }

    f32x16 o[4];
#pragma unroll
    for (int cq = 0; cq < 4; cq++)
#pragma unroll
        for (int r = 0; r < 16; r++) o[cq][r] = 0.f;

    float mst = -3.0e38f, lp = 0.f;

    const size_t vr0 = (size_t)(ch * 128 + l31) * M_;          // cq=0 row
    const size_t vr1 = (size_t)(ch * 128 + 32 + l31) * M_;     // cq=1 row
    const size_t vr2 = (size_t)(ch * 128 + 64 + l31) * M_;     // cq=2 row
    const size_t vr3 = (size_t)(ch * 128 + 96 + l31) * M_;     // cq=3 row

    for (int it = 0; it < M_ / MT; it++) {
        const int cur = it & 1, nxt = cur ^ 1;
        const int m0i = it * MT;
        // single barrier: own K(it) staging drained per-wave, then all waves synced
        asm volatile("s_waitcnt vmcnt(0) lgkmcnt(0)" ::: "memory");
        __builtin_amdgcn_s_barrier();

        // ---- V first half (cq 0,1), issued FIRST -> hidden under QK^T ----
        // A-frag: row = l31 -> c ; k = ks*16 + hh*8 + i -> m
        f16x8 vA0[4], vA1[4];
#pragma unroll
        for (int ks = 0; ks < 4; ks++) {
            vA0[ks] = *(const f16x8*)(srcVb + vr0 + m0i + ks * 16 + hh * 8);
            vA1[ks] = *(const f16x8*)(srcVb + vr1 + m0i + ks * 16 + hh * 8);
        }
        __builtin_amdgcn_sched_barrier(0);   // pin vA-issue before K-issue

        // ---- K(it+1) prefetch ----
        if (it + 1 < M_ / MT) {
            const _Float16* srcK = srcKb + (size_t)(m0i + MT) * C_;
#pragma unroll
            for (int j = 0; j < 4; j++) {
                int row = w * 8 + j * 2 + hh;
                int logi = l31 ^ (row & 31);
                async16(srcK + (size_t)row * C_ + logi * 8, &sK[nxt][(w * 8 + j * 2) * 256]);
            }
        }

        // ---- S^T = K·Q^T for full 64 m x 32 n (2 quadrant accumulators) ----
        // C/D: col = l31 = n ; row(m) = mh*32 + (reg&3) + 8*(reg>>2) + 4*hh
        f32x16 sm0, sm1;
#pragma unroll
        for (int r = 0; r < 16; r++) { sm0[r] = 0.f; sm1[r] = 0.f; }
        __builtin_amdgcn_s_setprio(1);
#pragma unroll
        for (int ks = 0; ks < 16; ks++) {
            f16x8 bk0 = *(const f16x8*)(&sK[cur][(l31) * 256 + (((ks * 2 + hh) ^ l31) << 3)]);
            sm0 = __builtin_amdgcn_mfma_f32_32x32x16_f16(bk0, qf[ks], sm0, 0, 0, 0);
            f16x8 bk1 = *(const f16x8*)(&sK[cur][(32 + l31) * 256 + (((ks * 2 + hh) ^ l31) << 3)]);
            sm1 = __builtin_amdgcn_mfma_f32_32x32x16_f16(bk1, qf[ks], sm1, 0, 0, 0);
        }
        __builtin_amdgcn_s_setprio(0);

        // ---- in-register online softmax (lane pair l/l^32 holds all 64 m) ----
        float tm[8];
#pragma unroll
        for (int j = 0; j < 8; j++)
            tm[j] = fmaxf(fmaxf(sm0[j], sm0[j + 8]), fmaxf(sm1[j], sm1[j + 8]));
#pragma unroll
        for (int j = 0; j < 4; j++) tm[j] = fmaxf(tm[j], tm[j + 4]);
        float rowmax = fmaxf(fmaxf(tm[0], tm[1]), fmaxf(tm[2], tm[3]));
        rowmax = fmaxf(rowmax, __shfl_xor(rowmax, 32, 64));
        float al = 1.0f;
        if (rowmax > mst) { al = exp2f((mst - rowmax) * L2E); mst = rowmax; }
        const float mb = mst * L2E;
#pragma unroll
        for (int r = 0; r < 16; r++) {
            sm0[r] = exp2f(sm0[r] * L2E - mb);
            sm1[r] = exp2f(sm1[r] * L2E - mb);
        }
        float tp[8];
#pragma unroll
        for (int j = 0; j < 8; j++)
            tp[j] = (sm0[j] + sm0[j + 8]) + (sm1[j] + sm1[j + 8]);
#pragma unroll
        for (int j = 0; j < 4; j++) tp[j] += tp[j + 4];
        float ps = (tp[0] + tp[1]) + (tp[2] + tp[3]);
        ps += __shfl_xor(ps, 32, 64);
        lp = lp * al + ps;

        if (al != 1.0f) {
#pragma unroll
            for (int cq = 0; cq < 4; cq++)
#pragma unroll
                for (int r = 0; r < 16; r++) o[cq][r] *= al;
        }

        // ---- pack P -> PV B-frags in registers (no LDS); sm dies here ----
        f16x8 pfr0, pfr1, pfr2, pfr3;
        {
            unsigned pk[8];
#pragma unroll
            for (int j = 0; j < 8; j++) {
                f16x2 pr;
                pr[0] = (_Float16)sm0[2 * j];
                pr[1] = (_Float16)sm0[2 * j + 1];
                pk[j] = __builtin_bit_cast(unsigned, pr);
            }
            plswap(pk[0], pk[2]);
            plswap(pk[1], pk[3]);
            plswap(pk[4], pk[6]);
            plswap(pk[5], pk[7]);
            u32x4 t0, t1;
            t0[0] = pk[0]; t0[1] = pk[1]; t0[2] = pk[2]; t0[3] = pk[3];
            t1[0] = pk[4]; t1[1] = pk[5]; t1[2] = pk[6]; t1[3] = pk[7];
            pfr0 = __builtin_bit_cast(f16x8, t0);
            pfr1 = __builtin_bit_cast(f16x8, t1);
        }
        {
            unsigned pk[8];
#pragma unroll
            for (int j = 0; j < 8; j++) {
                f16x2 pr;
                pr[0] = (_Float16)sm1[2 * j];
                pr[1] = (_Float16)sm1[2 * j + 1];
                pk[j] = __builtin_bit_cast(unsigned, pr);
            }
            plswap(pk[0], pk[2]);
            plswap(pk[1], pk[3]);
            plswap(pk[4], pk[6]);
            plswap(pk[5], pk[7]);
            u32x4 t0, t1;
            t0[0] = pk[0]; t0[1] = pk[1]; t0[2] = pk[2]; t0[3] = pk[3];
            t1[0] = pk[4]; t1[1] = pk[5]; t1[2] = pk[6]; t1[3] = pk[7];
            pfr2 = __builtin_bit_cast(f16x8, t0);
            pfr3 = __builtin_bit_cast(f16x8, t1);
        }

        // ---- V second half (cq 2,3) issued now -> hidden under PV first half ----
        f16x8 vB2[4], vB3[4];
#pragma unroll
        for (int ks = 0; ks < 4; ks++) {
            vB2[ks] = *(const f16x8*)(srcVb + vr2 + m0i + ks * 16 + hh * 8);
            vB3[ks] = *(const f16x8*)(srcVb + vr3 + m0i + ks * 16 + hh * 8);
        }
        __builtin_amdgcn_sched_barrier(0);   // pin vB-issue before PV MFMAs

        // ---- O += V·P^T (pure register MFMA; LDS idle) ----
        __builtin_amdgcn_s_setprio(1);
        o[0] = __builtin_amdgcn_mfma_f32_32x32x16_f16(vA0[0], pfr0, o[0], 0, 0, 0);
        o[1] = __builtin_amdgcn_mfma_f32_32x32x16_f16(vA1[0], pfr0, o[1], 0, 0, 0);
        o[0] = __builtin_amdgcn_mfma_f32_32x32x16_f16(vA0[1], pfr1, o[0], 0, 0, 0);
        o[1] = __builtin_amdgcn_mfma_f32_32x32x16_f16(vA1[1], pfr1, o[1], 0, 0, 0);
        o[0] = __builtin_amdgcn_mfma_f32_32x32x16_f16(vA0[2], pfr2, o[0], 0, 0, 0);
        o[1] = __builtin_amdgcn_mfma_f32_32x32x16_f16(vA1[2], pfr2, o[1], 0, 0, 0);
        o[0] = __builtin_amdgcn_mfma_f32_32x32x16_f16(vA0[3], pfr3, o[0], 0, 0, 0);
        o[1] = __builtin_amdgcn_mfma_f32_32x32x16_f16(vA1[3], pfr3, o[1], 0, 0, 0);
        o[2] = __builtin_amdgcn_mfma_f32_32x32x16_f16(vB2[0], pfr0, o[2], 0, 0, 0);
        o[3] = __builtin_amdgcn_mfma_f32_32x32x16_f16(vB3[0], pfr0, o[3], 0, 0, 0);
        o[2] = __builtin_amdgcn_mfma_f32_32x32x16_f16(vB2[1], pfr1, o[2], 0, 0, 0);
        o[3] = __builtin_amdgcn_mfma_f32_32x32x16_f16(vB3[1], pfr1, o[3], 0, 0, 0);
        o[2] = __builtin_amdgcn_mfma_f32_32x32x16_f16(vB2[2], pfr2, o[2], 0, 0, 0);
        o[3] = __builtin_amdgcn_mfma_f32_32x32x16_f16(vB3[2], pfr2, o[3], 0, 0, 0);
        o[2] = __builtin_amdgcn_mfma_f32_32x32x16_f16(vB2[3], pfr3, o[2], 0, 0, 0);
        o[3] = __builtin_amdgcn_mfma_f32_32x32x16_f16(vB3[3], pfr3, o[3], 0, 0, 0);
        __builtin_amdgcn_s_setprio(0);
    }

    // ---- epilogue: fully lane-local normalize + store ----
    const float linv = 1.0f / lp;
#pragma unroll
    for (int cq = 0; cq < 4; cq++)
#pragma unroll
        for (int r = 0; r < 16; r++) {
            int c = ch * 128 + cq * 32 + (r & 3) + 8 * (r >> 2) + 4 * hh;
            out[((size_t)(b * C_ + c)) * N_ + n0 + ns * 32 + l31] = o[cq][r] * linv;
        }
}

extern "C" void kernel_launch(void* const* d_in, const int* in_sizes, int n_in,
                              void* d_out, int out_size, void* d_ws, size_t ws_size,
                              hipStream_t stream) {
    const float* h  = (const float*)d_in[0];
    const float* xs = (const float*)d_in[1];
    const float* ys = (const float*)d_in[2];
    float* out = (float*)d_out;

    _Float16* kt  = (_Float16*)d_ws;                    // [B,M,C] fp16: 16 MB
    _Float16* vbb = kt + (size_t)B_ * M_ * C_;          // [B,C,M] fp16: 16 MB

    kPre<<<dim3(2048 + 8192), 256, 0, stream>>>(xs, ys, kt, vbb);
    kAttn<<<dim3(B_ * (N_ / NT)), 512, 0, stream>>>(h, kt, vbb, out);
}